// Round 2
// baseline (447.212 us; speedup 1.0000x reference)
//
#include <hip/hip_runtime.h>
#include <hip/hip_bf16.h>

#define N_NODES 8192
#define E_EDGES 65536
#define HEADS 3
#define CDIM 384
#define NHC 1152
#define T_STEPS 12
#define D_IN 16
#define HID 32
#define PRED_LEN 6
#define OUT_LABEL_OFF 49152   // N_NODES*PRED_LEN elements

#define O_X        0u
#define O_WIH      1572864u
#define O_WHH      1574400u
#define O_BIH      1577472u
#define O_BHH      1577568u
#define O_WGAT     1577664u
#define O_ATTS     2020032u
#define O_ATTD     2021184u
#define O_WEDGE    2022336u
#define O_ATTE     2023488u
#define O_GBIAS    2024640u
#define O_WP1      2025024u
#define O_BP1      2025056u
#define O_WP3      2025057u
#define O_BP3      2025129u
#define O_WC1      2025135u
#define O_BC1      2037423u
#define O_WC2      2037455u
#define O_BC2      2037519u
#define O_EATTR    2037521u
#define CONV_TOTAL 2103057u

#define O_GATIN    2103072u
#define O_HFEAT    5248800u
#define O_ASRC     14685984u
#define O_ADST     14710560u
#define O_ARAW     14735136u
#define O_WEXP     14931744u
#define O_AMAX     15128352u
#define O_DENOM    15152928u
#define O_GMEAN    15177504u
#define O_POOLED   18323232u
#define O_KH       18326304u
#define O_FLAG     18326307u

__device__ __forceinline__ float b2f(unsigned short u) {
    return __uint_as_float(((unsigned)u) << 16);
}
__device__ __forceinline__ unsigned enc_f(float f) {
    unsigned u = __float_as_uint(f);
    return (u & 0x80000000u) ? ~u : (u | 0x80000000u);
}
__device__ __forceinline__ float dec_f(unsigned e) {
    return __uint_as_float((e & 0x80000000u) ? (e & 0x7FFFFFFFu) : ~e);
}

__global__ void detect_kernel(const unsigned short* __restrict__ wih_raw,
                              int* __restrict__ flag)
{
    int lane = threadIdx.x;
    int cnt = 0;
#pragma unroll
    for (int i = 0; i < 8; i++) {
        unsigned short h = wih_raw[(lane * 8 + i) * 2];
        int e = (h >> 7) & 0xFF;
        if (e >= 100 && e <= 127) cnt++;
    }
#pragma unroll
    for (int off = 32; off; off >>= 1) cnt += __shfl_down(cnt, off, 64);
    if (lane == 0) *flag = (cnt >= 300) ? 1 : 0;
}

__global__ __launch_bounds__(256) void convert_all(
    const int* __restrict__ flag,
    const void* x, const void* Wih, const void* Whh, const void* bih, const void* bhh,
    const void* Wgat, const void* atts, const void* attd, const void* Wedge, const void* atte,
    const void* gbias, const void* Wp1, const void* bp1, const void* Wp3, const void* bp3,
    const void* Wc1, const void* bc1, const void* Wc2, const void* bc2, const void* eattr,
    float* __restrict__ dst)
{
    unsigned idx = blockIdx.x * 256 + threadIdx.x;
    if (idx >= CONV_TOTAL) return;
    const void* src; unsigned off;
    if      (idx < O_WIH)   { src = x;     off = idx - O_X; }
    else if (idx < O_WHH)   { src = Wih;   off = idx - O_WIH; }
    else if (idx < O_BIH)   { src = Whh;   off = idx - O_WHH; }
    else if (idx < O_BHH)   { src = bih;   off = idx - O_BIH; }
    else if (idx < O_WGAT)  { src = bhh;   off = idx - O_BHH; }
    else if (idx < O_ATTS)  { src = Wgat;  off = idx - O_WGAT; }
    else if (idx < O_ATTD)  { src = atts;  off = idx - O_ATTS; }
    else if (idx < O_WEDGE) { src = attd;  off = idx - O_ATTD; }
    else if (idx < O_ATTE)  { src = Wedge; off = idx - O_WEDGE; }
    else if (idx < O_GBIAS) { src = atte;  off = idx - O_ATTE; }
    else if (idx < O_WP1)   { src = gbias; off = idx - O_GBIAS; }
    else if (idx < O_BP1)   { src = Wp1;   off = idx - O_WP1; }
    else if (idx < O_WP3)   { src = bp1;   off = idx - O_BP1; }
    else if (idx < O_BP3)   { src = Wp3;   off = idx - O_WP3; }
    else if (idx < O_WC1)   { src = bp3;   off = idx - O_BP3; }
    else if (idx < O_BC1)   { src = Wc1;   off = idx - O_WC1; }
    else if (idx < O_WC2)   { src = bc1;   off = idx - O_BC1; }
    else if (idx < O_BC2)   { src = Wc2;   off = idx - O_WC2; }
    else if (idx < O_EATTR) { src = bc2;   off = idx - O_BC2; }
    else                    { src = eattr; off = idx - O_EATTR; }
    float v = (*flag) ? b2f(((const unsigned short*)src)[off])
                      : ((const float*)src)[off];
    dst[idx] = v;
}

__global__ __launch_bounds__(256) void gru_kernel(
    const float* __restrict__ xf,
    const float* __restrict__ Wih,
    const float* __restrict__ Whh,
    const float* __restrict__ bih,
    const float* __restrict__ bhh,
    float* __restrict__ gat_in)
{
    int gid = blockIdx.x * 256 + threadIdx.x;
    int n = gid >> 5;
    int j = gid & 31;

    float wih[3][16], whh[3][32], bi[3], bh[3];
#pragma unroll
    for (int g = 0; g < 3; g++) {
        int row = g * 32 + j;
#pragma unroll
        for (int i = 0; i < 16; i++) wih[g][i] = Wih[row * 16 + i];
#pragma unroll
        for (int i = 0; i < 32; i++) whh[g][i] = Whh[row * 32 + i];
        bi[g] = bih[row];
        bh[g] = bhh[row];
    }

    float hval = 0.f;
    float hloc[32];
#pragma unroll
    for (int i = 0; i < 32; i++) hloc[i] = 0.f;

    const float4* x4 = (const float4*)(xf + (size_t)n * 192);

    for (int t = 0; t < T_STEPS; t++) {
        float xv[16];
#pragma unroll
        for (int q = 0; q < 4; q++) {
            float4 p = x4[t * 4 + q];
            xv[q * 4 + 0] = p.x; xv[q * 4 + 1] = p.y;
            xv[q * 4 + 2] = p.z; xv[q * 4 + 3] = p.w;
        }

        float ir = bi[0], iz = bi[1], in_ = bi[2];
#pragma unroll
        for (int i = 0; i < 16; i++) {
            ir  += wih[0][i] * xv[i];
            iz  += wih[1][i] * xv[i];
            in_ += wih[2][i] * xv[i];
        }
        float hr = bh[0], hz = bh[1], hn = bh[2];
#pragma unroll
        for (int i = 0; i < 32; i++) {
            hr += whh[0][i] * hloc[i];
            hz += whh[1][i] * hloc[i];
            hn += whh[2][i] * hloc[i];
        }
        float r = 1.f / (1.f + expf(-(ir + hr)));
        float z = 1.f / (1.f + expf(-(iz + hz)));
        float nn = tanhf(in_ + r * hn);
        hval = (1.f - z) * nn + z * hval;

        gat_in[(size_t)n * 384 + t * 32 + j] = hval;
#pragma unroll
        for (int i = 0; i < 32; i++) hloc[i] = __shfl(hval, i, 32);
    }
}

#define BM 64
#define BN 64
#define BK 32
__global__ __launch_bounds__(256) void gemm_h_kernel(
    const float* __restrict__ A,
    const float* __restrict__ Bf,
    float* __restrict__ Cout)
{
    __shared__ float Ast[BK][BM + 4];
    __shared__ float Bst[BK][BN + 4];
    int tid = threadIdx.x;
    int tx = tid & 15, ty = tid >> 4;
    int m0 = blockIdx.x * BM;
    int j0 = blockIdx.y * BN;

    int ar = tid >> 2;
    int ac = (tid & 3) * 8;

    float acc[4][4] = {};

    for (int k0 = 0; k0 < 384; k0 += BK) {
        float4 a0 = *(const float4*)(A + (size_t)(m0 + ar) * 384 + k0 + ac);
        float4 a1 = *(const float4*)(A + (size_t)(m0 + ar) * 384 + k0 + ac + 4);
        float4 b0 = *(const float4*)(Bf + (size_t)(j0 + ar) * 384 + k0 + ac);
        float4 b1 = *(const float4*)(Bf + (size_t)(j0 + ar) * 384 + k0 + ac + 4);

        __syncthreads();
        Ast[ac + 0][ar] = a0.x; Ast[ac + 1][ar] = a0.y;
        Ast[ac + 2][ar] = a0.z; Ast[ac + 3][ar] = a0.w;
        Ast[ac + 4][ar] = a1.x; Ast[ac + 5][ar] = a1.y;
        Ast[ac + 6][ar] = a1.z; Ast[ac + 7][ar] = a1.w;
        Bst[ac + 0][ar] = b0.x; Bst[ac + 1][ar] = b0.y;
        Bst[ac + 2][ar] = b0.z; Bst[ac + 3][ar] = b0.w;
        Bst[ac + 4][ar] = b1.x; Bst[ac + 5][ar] = b1.y;
        Bst[ac + 6][ar] = b1.z; Bst[ac + 7][ar] = b1.w;
        __syncthreads();

#pragma unroll
        for (int kk = 0; kk < BK; kk++) {
            float4 av = *(const float4*)&Ast[kk][ty * 4];
            float4 bv = *(const float4*)&Bst[kk][tx * 4];
            acc[0][0] += av.x * bv.x; acc[0][1] += av.x * bv.y; acc[0][2] += av.x * bv.z; acc[0][3] += av.x * bv.w;
            acc[1][0] += av.y * bv.x; acc[1][1] += av.y * bv.y; acc[1][2] += av.y * bv.z; acc[1][3] += av.y * bv.w;
            acc[2][0] += av.z * bv.x; acc[2][1] += av.z * bv.y; acc[2][2] += av.z * bv.z; acc[2][3] += av.z * bv.w;
            acc[3][0] += av.w * bv.x; acc[3][1] += av.w * bv.y; acc[3][2] += av.w * bv.z; acc[3][3] += av.w * bv.w;
        }
    }
#pragma unroll
    for (int i = 0; i < 4; i++) {
        float4 v = make_float4(acc[i][0], acc[i][1], acc[i][2], acc[i][3]);
        *(float4*)(Cout + (size_t)(m0 + ty * 4 + i) * NHC + j0 + tx * 4) = v;
    }
}

__global__ __launch_bounds__(256) void att_score_kernel(
    const float* __restrict__ h_feat,
    const float* __restrict__ att_src,
    const float* __restrict__ att_dst,
    float* __restrict__ a_src, float* __restrict__ a_dst)
{
    int w = (blockIdx.x * 256 + threadIdx.x) >> 6;
    int lane = threadIdx.x & 63;
    int n = w / 3, hd = w % 3;
    const float* hrow = h_feat + (size_t)n * NHC + hd * CDIM;
    float s0 = 0.f, s1 = 0.f;
#pragma unroll
    for (int q = 0; q < 6; q++) {
        int c = lane + q * 64;
        float hv = hrow[c];
        s0 += hv * att_src[hd * CDIM + c];
        s1 += hv * att_dst[hd * CDIM + c];
    }
#pragma unroll
    for (int off = 32; off; off >>= 1) {
        s0 += __shfl_down(s0, off, 64);
        s1 += __shfl_down(s1, off, 64);
    }
    if (lane == 0) { a_src[n * 3 + hd] = s0; a_dst[n * 3 + hd] = s1; }
}

__global__ void edge_const_kernel(const float* __restrict__ Wedge,
                                  const float* __restrict__ att_edge,
                                  float* __restrict__ Kh)
{
    int hd = threadIdx.x >> 6, lane = threadIdx.x & 63;
    float s = 0.f;
#pragma unroll
    for (int q = 0; q < 6; q++) {
        int c = lane + q * 64;
        s += Wedge[hd * CDIM + c] * att_edge[hd * CDIM + c];
    }
#pragma unroll
    for (int off = 32; off; off >>= 1) s += __shfl_down(s, off, 64);
    if (lane == 0) Kh[hd] = s;
}

__global__ __launch_bounds__(256) void edge_score_kernel(
    const int* __restrict__ edge_index,
    const float* __restrict__ edge_attr,
    const float* __restrict__ a_src, const float* __restrict__ a_dst,
    const float* __restrict__ Kh,
    float* __restrict__ a_raw, unsigned* __restrict__ amax_enc)
{
    int tid = blockIdx.x * 256 + threadIdx.x;
    int hd = tid >> 16;
    int e = tid & (E_EDGES - 1);
    int src = edge_index[e];
    int dst = edge_index[E_EDGES + e];
    float a = a_src[src * 3 + hd] + a_dst[dst * 3 + hd] + edge_attr[e] * Kh[hd];
    a = a > 0.f ? a : 0.2f * a;
    a_raw[hd * E_EDGES + e] = a;
    atomicMax(&amax_enc[dst * 3 + hd], enc_f(a));
}

__global__ __launch_bounds__(256) void edge_exp_kernel(
    const int* __restrict__ edge_index,
    const float* __restrict__ a_raw, const unsigned* __restrict__ amax_enc,
    float* __restrict__ w_exp, float* __restrict__ denom)
{
    int tid = blockIdx.x * 256 + threadIdx.x;
    int hd = tid >> 16;
    int e = tid & (E_EDGES - 1);
    int dst = edge_index[E_EDGES + e];
    float m = dec_f(amax_enc[dst * 3 + hd]);
    float w = expf(a_raw[hd * E_EDGES + e] - m);
    w_exp[hd * E_EDGES + e] = w;
    unsafeAtomicAdd(&denom[dst * 3 + hd], w);
}

__global__ __launch_bounds__(128) void aggregate_kernel(
    const int* __restrict__ edge_index,
    const float* __restrict__ h_feat,
    const float* __restrict__ w_exp, const float* __restrict__ denom,
    float* __restrict__ gmean)
{
    int e = blockIdx.x;
    int src = edge_index[e];
    int dst = edge_index[E_EDGES + e];
    const float third = 1.f / 3.f;
    float c0 = w_exp[e]               / (denom[dst * 3 + 0] + 1e-16f) * third;
    float c1 = w_exp[E_EDGES + e]     / (denom[dst * 3 + 1] + 1e-16f) * third;
    float c2 = w_exp[2 * E_EDGES + e] / (denom[dst * 3 + 2] + 1e-16f) * third;
    const float* hs = h_feat + (size_t)src * NHC;
    float* od = gmean + (size_t)dst * CDIM;
#pragma unroll
    for (int k = 0; k < 3; k++) {
        int c = threadIdx.x + k * 128;
        float v = c0 * hs[c] + c1 * hs[c + CDIM] + c2 * hs[c + 2 * CDIM];
        unsafeAtomicAdd(&od[c], v);
    }
}

__global__ __launch_bounds__(384) void pred_kernel(
    const int* __restrict__ flag,
    const float* __restrict__ gmean,
    const float* __restrict__ gat_bias,
    const float* __restrict__ Wp1, const float* __restrict__ bp1,
    const float* __restrict__ Wp3, const float* __restrict__ bp3,
    unsigned* __restrict__ pooled_enc,
    void* __restrict__ out_pred)
{
    __shared__ float gs[384];
    __shared__ float ps[12];
    int n = blockIdx.x;
    int tid = threadIdx.x;
    float g = gmean[(size_t)n * CDIM + tid] + gat_bias[tid];
    gs[tid] = g;
    atomicMax(&pooled_enc[(n >> 10) * CDIM + tid], enc_f(g));
    __syncthreads();

    int t = tid >> 5, c = tid & 31;
    float v = gs[t * 32 + c] * Wp1[c];
#pragma unroll
    for (int off = 16; off; off >>= 1) v += __shfl_down(v, off, 32);
    if (c == 0) { float p = v + bp1[0]; ps[t] = p > 0.f ? p : 0.f; }
    __syncthreads();

    if (tid < PRED_LEN) {
        float acc = bp3[tid];
#pragma unroll
        for (int tt = 0; tt < 12; tt++) acc += Wp3[tid * 12 + tt] * ps[tt];
        acc = acc > 0.f ? acc : 0.f;
        size_t oi = (size_t)n * PRED_LEN + tid;
        if (*flag) ((__hip_bfloat16*)out_pred)[oi] = __float2bfloat16(acc);
        else       ((float*)out_pred)[oi] = acc;
    }
}

__global__ __launch_bounds__(256) void cls_kernel(
    const int* __restrict__ flag,
    const unsigned* __restrict__ pooled_enc,
    const float* __restrict__ Wc1, const float* __restrict__ bc1,
    const float* __restrict__ Wc2, const float* __restrict__ bc2,
    void* __restrict__ out_base)
{
    __shared__ float l1s[8][32];
    int b = threadIdx.x >> 5, i = threadIdx.x & 31;
    float acc = bc1[i];
    for (int c = 0; c < CDIM; c++)
        acc += Wc1[i * CDIM + c] * dec_f(pooled_enc[b * CDIM + c]);
    l1s[b][i] = acc;
    __syncthreads();
    if (threadIdx.x < 8) {
        int bb = threadIdx.x;
        float l0 = bc2[0], l1v = bc2[1];
#pragma unroll
        for (int ii = 0; ii < 32; ii++) {
            l0  += Wc2[ii] * l1s[bb][ii];
            l1v += Wc2[32 + ii] * l1s[bb][ii];
        }
        float m = fmaxf(l0, l1v);
        float e0 = expf(l0 - m), e1 = expf(l1v - m);
        float s = e0 + e1;
        if (*flag) {
            __hip_bfloat16* ob = (__hip_bfloat16*)out_base;
            ob[OUT_LABEL_OFF + bb * 2 + 0] = __float2bfloat16(e0 / s);
            ob[OUT_LABEL_OFF + bb * 2 + 1] = __float2bfloat16(e1 / s);
        } else {
            float* of = (float*)out_base;
            of[OUT_LABEL_OFF + bb * 2 + 0] = e0 / s;
            of[OUT_LABEL_OFF + bb * 2 + 1] = e1 / s;
        }
    }
}

extern "C" void kernel_launch(void* const* d_in, const int* in_sizes, int n_in,
                              void* d_out, int out_size, void* d_ws, size_t ws_size,
                              hipStream_t stream) {
    float* W = (float*)d_ws;
    int* flag = (int*)(W + O_FLAG);
    const int* edge_index = (const int*)d_in[1];

    size_t zero_floats = (size_t)(O_POOLED + 8 * CDIM) - O_AMAX;
    hipMemsetAsync(W + O_AMAX, 0, zero_floats * 4, stream);

    detect_kernel<<<1, 64, 0, stream>>>((const unsigned short*)d_in[5], flag);
    convert_all<<<(CONV_TOTAL + 255) / 256, 256, 0, stream>>>(
        flag,
        d_in[0], d_in[5], d_in[6], d_in[7], d_in[8],
        d_in[9], d_in[10], d_in[11], d_in[12], d_in[13],
        d_in[14], d_in[15], d_in[16], d_in[17], d_in[18],
        d_in[19], d_in[20], d_in[21], d_in[22], d_in[2],
        W);

    gru_kernel<<<N_NODES * 32 / 256, 256, 0, stream>>>(
        W + O_X, W + O_WIH, W + O_WHH, W + O_BIH, W + O_BHH, W + O_GATIN);
    gemm_h_kernel<<<dim3(N_NODES / BM, NHC / BN), 256, 0, stream>>>(
        W + O_GATIN, W + O_WGAT, W + O_HFEAT);
    att_score_kernel<<<(N_NODES * 3 * 64) / 256, 256, 0, stream>>>(
        W + O_HFEAT, W + O_ATTS, W + O_ATTD, W + O_ASRC, W + O_ADST);
    edge_const_kernel<<<1, 192, 0, stream>>>(W + O_WEDGE, W + O_ATTE, W + O_KH);
    edge_score_kernel<<<3 * E_EDGES / 256, 256, 0, stream>>>(
        edge_index, W + O_EATTR, W + O_ASRC, W + O_ADST, W + O_KH,
        W + O_ARAW, (unsigned*)(W + O_AMAX));
    edge_exp_kernel<<<3 * E_EDGES / 256, 256, 0, stream>>>(
        edge_index, W + O_ARAW, (const unsigned*)(W + O_AMAX),
        W + O_WEXP, W + O_DENOM);
    aggregate_kernel<<<E_EDGES, 128, 0, stream>>>(
        edge_index, W + O_HFEAT, W + O_WEXP, W + O_DENOM, W + O_GMEAN);
    pred_kernel<<<N_NODES, 384, 0, stream>>>(
        flag, W + O_GMEAN, W + O_GBIAS, W + O_WP1, W + O_BP1,
        W + O_WP3, W + O_BP3, (unsigned*)(W + O_POOLED), d_out);
    cls_kernel<<<1, 256, 0, stream>>>(
        flag, (const unsigned*)(W + O_POOLED),
        W + O_WC1, W + O_BC1, W + O_WC2, W + O_BC2, d_out);
}

// Round 3
// 325.219 us; speedup vs baseline: 1.3751x; 1.3751x over previous
//
#include <hip/hip_runtime.h>
#include <hip/hip_bf16.h>

#define N_NODES 8192
#define E_EDGES 65536
#define HEADS 3
#define CDIM 384
#define NHC 1152
#define T_STEPS 12
#define D_IN 16
#define HID 32
#define PRED_LEN 6
#define OUT_LABEL_OFF 49152   // N_NODES*PRED_LEN elements

#define O_X        0u
#define O_WIH      1572864u
#define O_WHH      1574400u
#define O_BIH      1577472u
#define O_BHH      1577568u
#define O_WGAT     1577664u
#define O_ATTS     2020032u
#define O_ATTD     2021184u
#define O_WEDGE    2022336u
#define O_ATTE     2023488u
#define O_GBIAS    2024640u
#define O_WP1      2025024u
#define O_BP1      2025056u
#define O_WP3      2025057u
#define O_BP3      2025129u
#define O_WC1      2025135u
#define O_BC1      2037423u
#define O_WC2      2037455u
#define O_BC2      2037519u
#define O_EATTR    2037521u
#define CONV_TOTAL 2103057u

#define O_GATIN    2103072u
// --- packed into the (now unused-as-f32) O_GATIN region (3145728 floats) ---
#define O_GATB     O_GATIN               // bf16 gat_in: 3145728 hw = 1572864 f32 slots
#define O_WGATB    (O_GATIN + 1572864u)  // bf16 Wgat: 442368 hw = 221184 slots
#define O_DEG      (O_GATIN + 1794048u)  // int [8192]
#define O_ROWST    (O_GATIN + 1802240u)  // int [8192]
#define O_CURS     (O_GATIN + 1810432u)  // int [8192]
#define O_CSRE     (O_GATIN + 1818624u)  // int [65536]
// ---------------------------------------------------------------------------
#define O_HFEAT    5248800u
#define O_ASRC     14685984u
#define O_ADST     14710560u
#define O_ARAW     14735136u
#define O_WEXP     14931744u
#define O_AMAX     15128352u
#define O_DENOM    15152928u
#define O_GMEAN    15177504u
#define O_POOLED   18323232u
#define O_KH       18326304u
#define O_FLAG     18326307u

typedef __attribute__((ext_vector_type(8))) short short8;
typedef __attribute__((ext_vector_type(4))) float floatx4;

__device__ __forceinline__ float b2f(unsigned short u) {
    return __uint_as_float(((unsigned)u) << 16);
}
__device__ __forceinline__ unsigned short f2b(float f) {
    __hip_bfloat16 b = __float2bfloat16(f);
    return *(unsigned short*)&b;
}
__device__ __forceinline__ unsigned enc_f(float f) {
    unsigned u = __float_as_uint(f);
    return (u & 0x80000000u) ? ~u : (u | 0x80000000u);
}
__device__ __forceinline__ float dec_f(unsigned e) {
    return __uint_as_float((e & 0x80000000u) ? (e & 0x7FFFFFFFu) : ~e);
}

__global__ void detect_kernel(const unsigned short* __restrict__ wih_raw,
                              int* __restrict__ flag)
{
    int lane = threadIdx.x;
    int cnt = 0;
#pragma unroll
    for (int i = 0; i < 8; i++) {
        unsigned short h = wih_raw[(lane * 8 + i) * 2];
        int e = (h >> 7) & 0xFF;
        if (e >= 100 && e <= 127) cnt++;
    }
#pragma unroll
    for (int off = 32; off; off >>= 1) cnt += __shfl_down(cnt, off, 64);
    if (lane == 0) *flag = (cnt >= 300) ? 1 : 0;
}

__global__ __launch_bounds__(256) void convert_all(
    const int* __restrict__ flag,
    const void* x, const void* Wih, const void* Whh, const void* bih, const void* bhh,
    const void* Wgat, const void* atts, const void* attd, const void* Wedge, const void* atte,
    const void* gbias, const void* Wp1, const void* bp1, const void* Wp3, const void* bp3,
    const void* Wc1, const void* bc1, const void* Wc2, const void* bc2, const void* eattr,
    float* __restrict__ dst)
{
    unsigned idx = blockIdx.x * 256 + threadIdx.x;
    if (idx >= CONV_TOTAL) return;
    const void* src; unsigned off;
    if      (idx < O_WIH)   { src = x;     off = idx - O_X; }
    else if (idx < O_WHH)   { src = Wih;   off = idx - O_WIH; }
    else if (idx < O_BIH)   { src = Whh;   off = idx - O_WHH; }
    else if (idx < O_BHH)   { src = bih;   off = idx - O_BIH; }
    else if (idx < O_WGAT)  { src = bhh;   off = idx - O_BHH; }
    else if (idx < O_ATTS)  { src = Wgat;  off = idx - O_WGAT; }
    else if (idx < O_ATTD)  { src = atts;  off = idx - O_ATTS; }
    else if (idx < O_WEDGE) { src = attd;  off = idx - O_ATTD; }
    else if (idx < O_ATTE)  { src = Wedge; off = idx - O_WEDGE; }
    else if (idx < O_GBIAS) { src = atte;  off = idx - O_ATTE; }
    else if (idx < O_WP1)   { src = gbias; off = idx - O_GBIAS; }
    else if (idx < O_BP1)   { src = Wp1;   off = idx - O_WP1; }
    else if (idx < O_BP3)   { src = (idx < O_BP1 + 1) ? bp1 : Wp3; off = (idx < O_BP1 + 1) ? 0 : idx - O_BP3 + 72; }
    else if (idx < O_WC1)   { src = bp3;   off = idx - O_BP3; }
    else if (idx < O_BC1)   { src = Wc1;   off = idx - O_WC1; }
    else if (idx < O_WC2)   { src = bc1;   off = idx - O_BC1; }
    else if (idx < O_BC2)   { src = Wc2;   off = idx - O_WC2; }
    else if (idx < O_EATTR) { src = bc2;   off = idx - O_BC2; }
    else                    { src = eattr; off = idx - O_EATTR; }
    // fix the O_BP1/O_WP3 fold (1-element bp1 then 72-element Wp3)
    if (idx >= O_BP1 && idx < O_BP3) {
        if (idx == O_BP1) { src = bp1; off = 0; }
        else              { src = Wp3; off = idx - O_WP3; }
    }
    float v = (*flag) ? b2f(((const unsigned short*)src)[off])
                      : ((const float*)src)[off];
    dst[idx] = v;
}

__global__ void cvt_wgat(const int* __restrict__ flag,
                         const void* __restrict__ Wg,
                         unsigned short* __restrict__ dstb)
{
    unsigned i = blockIdx.x * 256 + threadIdx.x;
    if (i >= 442368u) return;
    dstb[i] = (*flag) ? ((const unsigned short*)Wg)[i]
                      : f2b(((const float*)Wg)[i]);
}

// ---------------------------------------------------------------- GRU
// 32 threads/node; h broadcast via per-wave LDS (float4 reads, broadcast = conflict-free).
__global__ __launch_bounds__(256) void gru_kernel(
    const float* __restrict__ xf,
    const float* __restrict__ Wih,
    const float* __restrict__ Whh,
    const float* __restrict__ bih,
    const float* __restrict__ bhh,
    unsigned short* __restrict__ gat_b)   // [N,384] bf16
{
    __shared__ float hsh[8][32];
    int gid = blockIdx.x * 256 + threadIdx.x;
    int n = gid >> 5;
    int j = gid & 31;
    int wid = threadIdx.x >> 5;

    float wih[3][16], whh[3][32], bi[3], bh[3];
#pragma unroll
    for (int g = 0; g < 3; g++) {
        int row = g * 32 + j;
#pragma unroll
        for (int i = 0; i < 16; i++) wih[g][i] = Wih[row * 16 + i];
#pragma unroll
        for (int i = 0; i < 32; i++) whh[g][i] = Whh[row * 32 + i];
        bi[g] = bih[row];
        bh[g] = bhh[row];
    }

    float hval = 0.f;
    hsh[wid][j] = 0.f;

    const float4* x4 = (const float4*)(xf + (size_t)n * 192);

    for (int t = 0; t < T_STEPS; t++) {
        float xv[16];
#pragma unroll
        for (int q = 0; q < 4; q++) {
            float4 p = x4[t * 4 + q];
            xv[q * 4 + 0] = p.x; xv[q * 4 + 1] = p.y;
            xv[q * 4 + 2] = p.z; xv[q * 4 + 3] = p.w;
        }

        float ir = bi[0], iz = bi[1], in_ = bi[2];
#pragma unroll
        for (int i = 0; i < 16; i++) {
            ir  += wih[0][i] * xv[i];
            iz  += wih[1][i] * xv[i];
            in_ += wih[2][i] * xv[i];
        }
        float hr = bh[0], hz = bh[1], hn = bh[2];
#pragma unroll
        for (int q = 0; q < 8; q++) {
            float4 hv = *(const float4*)&hsh[wid][q * 4];
            hr += whh[0][q*4+0]*hv.x + whh[0][q*4+1]*hv.y + whh[0][q*4+2]*hv.z + whh[0][q*4+3]*hv.w;
            hz += whh[1][q*4+0]*hv.x + whh[1][q*4+1]*hv.y + whh[1][q*4+2]*hv.z + whh[1][q*4+3]*hv.w;
            hn += whh[2][q*4+0]*hv.x + whh[2][q*4+1]*hv.y + whh[2][q*4+2]*hv.z + whh[2][q*4+3]*hv.w;
        }
        float r = 1.f / (1.f + expf(-(ir + hr)));
        float z = 1.f / (1.f + expf(-(iz + hz)));
        float nn = tanhf(in_ + r * hn);
        hval = (1.f - z) * nn + z * hval;

        gat_b[(size_t)n * 384 + t * 32 + j] = f2b(hval);
        hsh[wid][j] = hval;   // wave-synchronous (both 32-groups live in one wave)
    }
}

// ---------------------------------------------------------------- MFMA GEMM
// C[m,n] = sum_k A[m,k]*Wg[n,k]; A bf16 [8192,384], Wg bf16 [1152,384], C f32.
// 128x128 tile, 4 waves (2x2 of 64x64), 16x16x32 bf16 MFMA, BK=32.
__global__ __launch_bounds__(256) void gemm_mfma(
    const unsigned short* __restrict__ Ab,
    const unsigned short* __restrict__ Bb,
    float* __restrict__ C)
{
    __shared__ unsigned short sA[128][40];   // +8 pad, row = 80 B (16B-aligned)
    __shared__ unsigned short sB[128][40];
    int tid = threadIdx.x;
    int wave = tid >> 6, lane = tid & 63;
    int wm = (wave >> 1) * 64, wn = (wave & 1) * 64;
    int m0 = blockIdx.x * 128, n0 = blockIdx.y * 128;

    int r0 = tid >> 2;            // 0..63
    int c8 = (tid & 3) * 8;       // 0,8,16,24

    floatx4 acc[4][4];
#pragma unroll
    for (int i = 0; i < 4; i++)
#pragma unroll
        for (int j = 0; j < 4; j++) acc[i][j] = 0;

    int ml = lane & 15, kq = (lane >> 4) * 8;

    for (int k0 = 0; k0 < 384; k0 += 32) {
        short8 a0 = *(const short8*)(Ab + (size_t)(m0 + r0) * 384 + k0 + c8);
        short8 a1 = *(const short8*)(Ab + (size_t)(m0 + r0 + 64) * 384 + k0 + c8);
        short8 b0 = *(const short8*)(Bb + (size_t)(n0 + r0) * 384 + k0 + c8);
        short8 b1 = *(const short8*)(Bb + (size_t)(n0 + r0 + 64) * 384 + k0 + c8);

        __syncthreads();
        *(short8*)(&sA[r0][c8])      = a0;
        *(short8*)(&sA[r0 + 64][c8]) = a1;
        *(short8*)(&sB[r0][c8])      = b0;
        *(short8*)(&sB[r0 + 64][c8]) = b1;
        __syncthreads();

        short8 af[4], bf[4];
#pragma unroll
        for (int i = 0; i < 4; i++)
            af[i] = *(const short8*)(&sA[wm + i * 16 + ml][kq]);
#pragma unroll
        for (int j = 0; j < 4; j++)
            bf[j] = *(const short8*)(&sB[wn + j * 16 + ml][kq]);
#pragma unroll
        for (int i = 0; i < 4; i++)
#pragma unroll
            for (int j = 0; j < 4; j++)
                acc[i][j] = __builtin_amdgcn_mfma_f32_16x16x32_bf16(af[i], bf[j], acc[i][j], 0, 0, 0);
    }

    int cn = lane & 15, rq = (lane >> 4) * 4;
#pragma unroll
    for (int i = 0; i < 4; i++)
#pragma unroll
        for (int j = 0; j < 4; j++)
#pragma unroll
            for (int r = 0; r < 4; r++)
                C[(size_t)(m0 + wm + i * 16 + rq + r) * NHC + n0 + wn + j * 16 + cn] = acc[i][j][r];
}

__global__ __launch_bounds__(256) void att_score_kernel(
    const float* __restrict__ h_feat,
    const float* __restrict__ att_src,
    const float* __restrict__ att_dst,
    float* __restrict__ a_src, float* __restrict__ a_dst)
{
    int w = (blockIdx.x * 256 + threadIdx.x) >> 6;
    int lane = threadIdx.x & 63;
    int n = w / 3, hd = w % 3;
    const float* hrow = h_feat + (size_t)n * NHC + hd * CDIM;
    float s0 = 0.f, s1 = 0.f;
#pragma unroll
    for (int q = 0; q < 6; q++) {
        int c = lane + q * 64;
        float hv = hrow[c];
        s0 += hv * att_src[hd * CDIM + c];
        s1 += hv * att_dst[hd * CDIM + c];
    }
#pragma unroll
    for (int off = 32; off; off >>= 1) {
        s0 += __shfl_down(s0, off, 64);
        s1 += __shfl_down(s1, off, 64);
    }
    if (lane == 0) { a_src[n * 3 + hd] = s0; a_dst[n * 3 + hd] = s1; }
}

__global__ void edge_const_kernel(const float* __restrict__ Wedge,
                                  const float* __restrict__ att_edge,
                                  float* __restrict__ Kh)
{
    int hd = threadIdx.x >> 6, lane = threadIdx.x & 63;
    float s = 0.f;
#pragma unroll
    for (int q = 0; q < 6; q++) {
        int c = lane + q * 64;
        s += Wedge[hd * CDIM + c] * att_edge[hd * CDIM + c];
    }
#pragma unroll
    for (int off = 32; off; off >>= 1) s += __shfl_down(s, off, 64);
    if (lane == 0) Kh[hd] = s;
}

// per-edge score + segment max; hd==0 threads also histogram dst degree
__global__ __launch_bounds__(256) void edge_score_kernel(
    const int* __restrict__ edge_index,
    const float* __restrict__ edge_attr,
    const float* __restrict__ a_src, const float* __restrict__ a_dst,
    const float* __restrict__ Kh,
    float* __restrict__ a_raw, unsigned* __restrict__ amax_enc,
    int* __restrict__ deg)
{
    int tid = blockIdx.x * 256 + threadIdx.x;
    int hd = tid >> 16;
    int e = tid & (E_EDGES - 1);
    int src = edge_index[e];
    int dst = edge_index[E_EDGES + e];
    float a = a_src[src * 3 + hd] + a_dst[dst * 3 + hd] + edge_attr[e] * Kh[hd];
    a = a > 0.f ? a : 0.2f * a;
    a_raw[hd * E_EDGES + e] = a;
    atomicMax(&amax_enc[dst * 3 + hd], enc_f(a));
    if (hd == 0) atomicAdd(&deg[dst], 1);
}

// exclusive scan of deg -> rowstart, cursor (single block)
__global__ __launch_bounds__(256) void scan_kernel(
    const int* __restrict__ deg, int* __restrict__ rowstart, int* __restrict__ cursor)
{
    __shared__ int ps[256];
    int t = threadIdx.x;
    int l[32], s = 0;
#pragma unroll
    for (int i = 0; i < 32; i++) { l[i] = deg[t * 32 + i]; s += l[i]; }
    ps[t] = s;
    __syncthreads();
    if (t == 0) {
        int run = 0;
        for (int i = 0; i < 256; i++) { int v = ps[i]; ps[i] = run; run += v; }
    }
    __syncthreads();
    int b = ps[t];
#pragma unroll
    for (int i = 0; i < 32; i++) {
        rowstart[t * 32 + i] = b;
        cursor[t * 32 + i] = b;
        b += l[i];
    }
}

// exp + segment sum; hd==0 threads also scatter edge id into CSR
__global__ __launch_bounds__(256) void edge_exp_kernel(
    const int* __restrict__ edge_index,
    const float* __restrict__ a_raw, const unsigned* __restrict__ amax_enc,
    float* __restrict__ w_exp, float* __restrict__ denom,
    int* __restrict__ cursor, int* __restrict__ csr_e)
{
    int tid = blockIdx.x * 256 + threadIdx.x;
    int hd = tid >> 16;
    int e = tid & (E_EDGES - 1);
    int dst = edge_index[E_EDGES + e];
    float m = dec_f(amax_enc[dst * 3 + hd]);
    float w = expf(a_raw[hd * E_EDGES + e] - m);
    w_exp[hd * E_EDGES + e] = w;
    unsafeAtomicAdd(&denom[dst * 3 + hd], w);
    if (hd == 0) {
        int pos = atomicAdd(&cursor[dst], 1);
        csr_e[pos] = e;
    }
}

// CSR aggregation: block per dst node, register accumulation, no atomics.
__global__ __launch_bounds__(384) void aggregate_csr(
    const int* __restrict__ edge_index,
    const float* __restrict__ h_feat,
    const float* __restrict__ w_exp, const float* __restrict__ denom,
    const int* __restrict__ rowstart, const int* __restrict__ deg,
    const int* __restrict__ csr_e,
    float* __restrict__ gmean)
{
    int dst = blockIdx.x;
    int s = rowstart[dst], d = deg[dst];
    int tid = threadIdx.x;
    const float third = 1.f / 3.f;
    float inv0 = third / (denom[dst * 3 + 0] + 1e-16f);
    float inv1 = third / (denom[dst * 3 + 1] + 1e-16f);
    float inv2 = third / (denom[dst * 3 + 2] + 1e-16f);
    __shared__ int ssrc[64];
    __shared__ float sc0[64], sc1[64], sc2[64];
    float a = 0.f;
    for (int ch = 0; ch < d; ch += 64) {
        int m = d - ch; if (m > 64) m = 64;
        __syncthreads();
        if (tid < m) {
            int e = csr_e[s + ch + tid];
            ssrc[tid] = edge_index[e];
            sc0[tid] = w_exp[e] * inv0;
            sc1[tid] = w_exp[E_EDGES + e] * inv1;
            sc2[tid] = w_exp[2 * E_EDGES + e] * inv2;
        }
        __syncthreads();
        for (int i = 0; i < m; i++) {
            const float* hs = h_feat + (size_t)ssrc[i] * NHC;
            a += sc0[i] * hs[tid] + sc1[i] * hs[tid + CDIM] + sc2[i] * hs[tid + 2 * CDIM];
        }
    }
    gmean[(size_t)dst * CDIM + tid] = a;
}

__global__ __launch_bounds__(384) void pred_kernel(
    const int* __restrict__ flag,
    const float* __restrict__ gmean,
    const float* __restrict__ gat_bias,
    const float* __restrict__ Wp1, const float* __restrict__ bp1,
    const float* __restrict__ Wp3, const float* __restrict__ bp3,
    unsigned* __restrict__ pooled_enc,
    void* __restrict__ out_pred)
{
    __shared__ float gs[384];
    __shared__ float ps[12];
    int n = blockIdx.x;
    int tid = threadIdx.x;
    float g = gmean[(size_t)n * CDIM + tid] + gat_bias[tid];
    gs[tid] = g;
    atomicMax(&pooled_enc[(n >> 10) * CDIM + tid], enc_f(g));
    __syncthreads();

    int t = tid >> 5, c = tid & 31;
    float v = gs[t * 32 + c] * Wp1[c];
#pragma unroll
    for (int off = 16; off; off >>= 1) v += __shfl_down(v, off, 32);
    if (c == 0) { float p = v + bp1[0]; ps[t] = p > 0.f ? p : 0.f; }
    __syncthreads();

    if (tid < PRED_LEN) {
        float acc = bp3[tid];
#pragma unroll
        for (int tt = 0; tt < 12; tt++) acc += Wp3[tid * 12 + tt] * ps[tt];
        acc = acc > 0.f ? acc : 0.f;
        size_t oi = (size_t)n * PRED_LEN + tid;
        if (*flag) ((__hip_bfloat16*)out_pred)[oi] = __float2bfloat16(acc);
        else       ((float*)out_pred)[oi] = acc;
    }
}

__global__ __launch_bounds__(256) void cls_kernel(
    const int* __restrict__ flag,
    const unsigned* __restrict__ pooled_enc,
    const float* __restrict__ Wc1, const float* __restrict__ bc1,
    const float* __restrict__ Wc2, const float* __restrict__ bc2,
    void* __restrict__ out_base)
{
    __shared__ float l1s[8][32];
    int b = threadIdx.x >> 5, i = threadIdx.x & 31;
    float acc = bc1[i];
    for (int c = 0; c < CDIM; c++)
        acc += Wc1[i * CDIM + c] * dec_f(pooled_enc[b * CDIM + c]);
    l1s[b][i] = acc;
    __syncthreads();
    if (threadIdx.x < 8) {
        int bb = threadIdx.x;
        float l0 = bc2[0], l1v = bc2[1];
#pragma unroll
        for (int ii = 0; ii < 32; ii++) {
            l0  += Wc2[ii] * l1s[bb][ii];
            l1v += Wc2[32 + ii] * l1s[bb][ii];
        }
        float m = fmaxf(l0, l1v);
        float e0 = expf(l0 - m), e1 = expf(l1v - m);
        float s = e0 + e1;
        if (*flag) {
            __hip_bfloat16* ob = (__hip_bfloat16*)out_base;
            ob[OUT_LABEL_OFF + bb * 2 + 0] = __float2bfloat16(e0 / s);
            ob[OUT_LABEL_OFF + bb * 2 + 1] = __float2bfloat16(e1 / s);
        } else {
            float* of = (float*)out_base;
            of[OUT_LABEL_OFF + bb * 2 + 0] = e0 / s;
            of[OUT_LABEL_OFF + bb * 2 + 1] = e1 / s;
        }
    }
}

extern "C" void kernel_launch(void* const* d_in, const int* in_sizes, int n_in,
                              void* d_out, int out_size, void* d_ws, size_t ws_size,
                              hipStream_t stream) {
    float* W = (float*)d_ws;
    int* flag = (int*)(W + O_FLAG);
    const int* edge_index = (const int*)d_in[1];

    size_t zero_floats = (size_t)(O_POOLED + 8 * CDIM) - O_AMAX;
    hipMemsetAsync(W + O_AMAX, 0, zero_floats * 4, stream);
    hipMemsetAsync(W + O_DEG, 0, 8192 * 4, stream);

    detect_kernel<<<1, 64, 0, stream>>>((const unsigned short*)d_in[5], flag);
    convert_all<<<(CONV_TOTAL + 255) / 256, 256, 0, stream>>>(
        flag,
        d_in[0], d_in[5], d_in[6], d_in[7], d_in[8],
        d_in[9], d_in[10], d_in[11], d_in[12], d_in[13],
        d_in[14], d_in[15], d_in[16], d_in[17], d_in[18],
        d_in[19], d_in[20], d_in[21], d_in[22], d_in[2],
        W);
    cvt_wgat<<<(442368 + 255) / 256, 256, 0, stream>>>(
        flag, d_in[9], (unsigned short*)(W + O_WGATB));

    gru_kernel<<<N_NODES * 32 / 256, 256, 0, stream>>>(
        W + O_X, W + O_WIH, W + O_WHH, W + O_BIH, W + O_BHH,
        (unsigned short*)(W + O_GATB));
    gemm_mfma<<<dim3(N_NODES / 128, NHC / 128), 256, 0, stream>>>(
        (const unsigned short*)(W + O_GATB),
        (const unsigned short*)(W + O_WGATB),
        W + O_HFEAT);
    att_score_kernel<<<(N_NODES * 3 * 64) / 256, 256, 0, stream>>>(
        W + O_HFEAT, W + O_ATTS, W + O_ATTD, W + O_ASRC, W + O_ADST);
    edge_const_kernel<<<1, 192, 0, stream>>>(W + O_WEDGE, W + O_ATTE, W + O_KH);
    edge_score_kernel<<<3 * E_EDGES / 256, 256, 0, stream>>>(
        edge_index, W + O_EATTR, W + O_ASRC, W + O_ADST, W + O_KH,
        W + O_ARAW, (unsigned*)(W + O_AMAX), (int*)(W + O_DEG));
    scan_kernel<<<1, 256, 0, stream>>>(
        (const int*)(W + O_DEG), (int*)(W + O_ROWST), (int*)(W + O_CURS));
    edge_exp_kernel<<<3 * E_EDGES / 256, 256, 0, stream>>>(
        edge_index, W + O_ARAW, (const unsigned*)(W + O_AMAX),
        W + O_WEXP, W + O_DENOM, (int*)(W + O_CURS), (int*)(W + O_CSRE));
    aggregate_csr<<<N_NODES, 384, 0, stream>>>(
        edge_index, W + O_HFEAT, W + O_WEXP, W + O_DENOM,
        (const int*)(W + O_ROWST), (const int*)(W + O_DEG),
        (const int*)(W + O_CSRE), W + O_GMEAN);
    pred_kernel<<<N_NODES, 384, 0, stream>>>(
        flag, W + O_GMEAN, W + O_GBIAS, W + O_WP1, W + O_BP1,
        W + O_WP3, W + O_BP3, (unsigned*)(W + O_POOLED), d_out);
    cls_kernel<<<1, 256, 0, stream>>>(
        flag, (const unsigned*)(W + O_POOLED),
        W + O_WC1, W + O_BC1, W + O_WC2, W + O_BC2, d_out);
}

// Round 4
// 284.459 us; speedup vs baseline: 1.5721x; 1.1433x over previous
//
#include <hip/hip_runtime.h>
#include <hip/hip_bf16.h>

#define N_NODES 8192
#define E_EDGES 65536
#define HEADS 3
#define CDIM 384
#define NHC 1152
#define T_STEPS 12
#define D_IN 16
#define HID 32
#define PRED_LEN 6
#define OUT_LABEL_OFF 49152   // N_NODES*PRED_LEN elements

#define O_X        0u
#define O_WIH      1572864u
#define O_WHH      1574400u
#define O_BIH      1577472u
#define O_BHH      1577568u
#define O_WGAT     1577664u
#define O_ATTS     2020032u
#define O_ATTD     2021184u
#define O_WEDGE    2022336u
#define O_ATTE     2023488u
#define O_GBIAS    2024640u
#define O_WP1      2025024u
#define O_BP1      2025056u
#define O_WP3      2025057u
#define O_BP3      2025129u
#define O_WC1      2025135u
#define O_BC1      2037423u
#define O_WC2      2037455u
#define O_BC2      2037519u
#define O_EATTR    2037521u
#define CONV_TOTAL 2103057u

#define O_GATIN    2103072u
#define O_GATB     O_GATIN               // bf16 gat_in [N,384]
#define O_WGATB    (O_GATIN + 1572864u)  // bf16 Wgat [1152,384]
#define O_DEG      (O_GATIN + 1794048u)  // int [8192]
#define O_ROWST    (O_GATIN + 1802240u)  // int [8192]
#define O_CURS     (O_GATIN + 1810432u)  // int [8192]
#define O_CSRE     (O_GATIN + 1818624u)  // int [65536]
#define O_HFEAT    5248800u              // bf16 h_feat [N,1152] (uses half the region)
#define O_ASRC     14685984u
#define O_ADST     14710560u
#define O_ARAW     14735136u
#define O_WEXP     14931744u
#define O_AMAX     15128352u
#define O_DENOM    15152928u
#define O_GMEAN    15177504u
#define O_POOLED   18323232u
#define O_KH       18326304u
#define O_FLAG     18326307u

typedef __attribute__((ext_vector_type(8))) short short8;
typedef __attribute__((ext_vector_type(4))) float floatx4;

__device__ __forceinline__ float b2f(unsigned short u) {
    return __uint_as_float(((unsigned)u) << 16);
}
__device__ __forceinline__ unsigned short f2b(float f) {
    __hip_bfloat16 b = __float2bfloat16(f);
    return *(unsigned short*)&b;
}
__device__ __forceinline__ unsigned enc_f(float f) {
    unsigned u = __float_as_uint(f);
    return (u & 0x80000000u) ? ~u : (u | 0x80000000u);
}
__device__ __forceinline__ float dec_f(unsigned e) {
    return __uint_as_float((e & 0x80000000u) ? (e & 0x7FFFFFFFu) : ~e);
}

__global__ void detect_kernel(const unsigned short* __restrict__ wih_raw,
                              int* __restrict__ flag)
{
    int lane = threadIdx.x;
    int cnt = 0;
#pragma unroll
    for (int i = 0; i < 8; i++) {
        unsigned short h = wih_raw[(lane * 8 + i) * 2];
        int e = (h >> 7) & 0xFF;
        if (e >= 100 && e <= 127) cnt++;
    }
#pragma unroll
    for (int off = 32; off; off >>= 1) cnt += __shfl_down(cnt, off, 64);
    if (lane == 0) *flag = (cnt >= 300) ? 1 : 0;
}

__global__ __launch_bounds__(256) void convert_all(
    const int* __restrict__ flag,
    const void* x, const void* Wih, const void* Whh, const void* bih, const void* bhh,
    const void* Wgat, const void* atts, const void* attd, const void* Wedge, const void* atte,
    const void* gbias, const void* Wp1, const void* bp1, const void* Wp3, const void* bp3,
    const void* Wc1, const void* bc1, const void* Wc2, const void* bc2, const void* eattr,
    float* __restrict__ dst)
{
    unsigned idx = blockIdx.x * 256 + threadIdx.x;
    if (idx >= CONV_TOTAL) return;
    const void* src; unsigned off;
    if      (idx < O_WIH)   { src = x;     off = idx - O_X; }
    else if (idx < O_WHH)   { src = Wih;   off = idx - O_WIH; }
    else if (idx < O_BIH)   { src = Whh;   off = idx - O_WHH; }
    else if (idx < O_BHH)   { src = bih;   off = idx - O_BIH; }
    else if (idx < O_WGAT)  { src = bhh;   off = idx - O_BHH; }
    else if (idx < O_ATTS)  { src = Wgat;  off = idx - O_WGAT; }
    else if (idx < O_ATTD)  { src = atts;  off = idx - O_ATTS; }
    else if (idx < O_WEDGE) { src = attd;  off = idx - O_ATTD; }
    else if (idx < O_ATTE)  { src = Wedge; off = idx - O_WEDGE; }
    else if (idx < O_GBIAS) { src = atte;  off = idx - O_ATTE; }
    else if (idx < O_WP1)   { src = gbias; off = idx - O_GBIAS; }
    else if (idx < O_BP1)   { src = Wp1;   off = idx - O_WP1; }
    else if (idx < O_BP3)   { src = (idx < O_BP1 + 1) ? bp1 : Wp3; off = (idx < O_BP1 + 1) ? 0 : idx - O_BP3 + 72; }
    else if (idx < O_WC1)   { src = bp3;   off = idx - O_BP3; }
    else if (idx < O_BC1)   { src = Wc1;   off = idx - O_WC1; }
    else if (idx < O_WC2)   { src = bc1;   off = idx - O_BC1; }
    else if (idx < O_BC2)   { src = Wc2;   off = idx - O_WC2; }
    else if (idx < O_EATTR) { src = bc2;   off = idx - O_BC2; }
    else                    { src = eattr; off = idx - O_EATTR; }
    if (idx >= O_BP1 && idx < O_BP3) {
        if (idx == O_BP1) { src = bp1; off = 0; }
        else              { src = Wp3; off = idx - O_WP3; }
    }
    float v = (*flag) ? b2f(((const unsigned short*)src)[off])
                      : ((const float*)src)[off];
    dst[idx] = v;
}

__global__ void cvt_wgat(const int* __restrict__ flag,
                         const void* __restrict__ Wg,
                         unsigned short* __restrict__ dstb)
{
    unsigned i = blockIdx.x * 256 + threadIdx.x;
    if (i >= 442368u) return;
    dstb[i] = (*flag) ? ((const unsigned short*)Wg)[i]
                      : f2b(((const float*)Wg)[i]);
}

// ---------------------------------------------------------------- GRU
__global__ __launch_bounds__(256) void gru_kernel(
    const float* __restrict__ xf,
    const float* __restrict__ Wih,
    const float* __restrict__ Whh,
    const float* __restrict__ bih,
    const float* __restrict__ bhh,
    unsigned short* __restrict__ gat_b)   // [N,384] bf16
{
    __shared__ float hsh[8][32];
    int gid = blockIdx.x * 256 + threadIdx.x;
    int n = gid >> 5;
    int j = gid & 31;
    int wid = threadIdx.x >> 5;

    float wih[3][16], whh[3][32], bi[3], bh[3];
#pragma unroll
    for (int g = 0; g < 3; g++) {
        int row = g * 32 + j;
#pragma unroll
        for (int i = 0; i < 16; i++) wih[g][i] = Wih[row * 16 + i];
#pragma unroll
        for (int i = 0; i < 32; i++) whh[g][i] = Whh[row * 32 + i];
        bi[g] = bih[row];
        bh[g] = bhh[row];
    }

    float hval = 0.f;
    hsh[wid][j] = 0.f;

    const float4* x4 = (const float4*)(xf + (size_t)n * 192);

    for (int t = 0; t < T_STEPS; t++) {
        float xv[16];
#pragma unroll
        for (int q = 0; q < 4; q++) {
            float4 p = x4[t * 4 + q];
            xv[q * 4 + 0] = p.x; xv[q * 4 + 1] = p.y;
            xv[q * 4 + 2] = p.z; xv[q * 4 + 3] = p.w;
        }

        float ir = bi[0], iz = bi[1], in_ = bi[2];
#pragma unroll
        for (int i = 0; i < 16; i++) {
            ir  += wih[0][i] * xv[i];
            iz  += wih[1][i] * xv[i];
            in_ += wih[2][i] * xv[i];
        }
        float hr = bh[0], hz = bh[1], hn = bh[2];
#pragma unroll
        for (int q = 0; q < 8; q++) {
            float4 hv = *(const float4*)&hsh[wid][q * 4];
            hr += whh[0][q*4+0]*hv.x + whh[0][q*4+1]*hv.y + whh[0][q*4+2]*hv.z + whh[0][q*4+3]*hv.w;
            hz += whh[1][q*4+0]*hv.x + whh[1][q*4+1]*hv.y + whh[1][q*4+2]*hv.z + whh[1][q*4+3]*hv.w;
            hn += whh[2][q*4+0]*hv.x + whh[2][q*4+1]*hv.y + whh[2][q*4+2]*hv.z + whh[2][q*4+3]*hv.w;
        }
        float r = 1.f / (1.f + expf(-(ir + hr)));
        float z = 1.f / (1.f + expf(-(iz + hz)));
        float nn = tanhf(in_ + r * hn);
        hval = (1.f - z) * nn + z * hval;

        gat_b[(size_t)n * 384 + t * 32 + j] = f2b(hval);
        hsh[wid][j] = hval;
    }
}

// ---------------------------------------------------------------- MFMA GEMM, bf16 output
__global__ __launch_bounds__(256) void gemm_mfma(
    const unsigned short* __restrict__ Ab,
    const unsigned short* __restrict__ Bb,
    unsigned short* __restrict__ Cb)
{
    __shared__ unsigned short sA[128][40];
    __shared__ unsigned short sB[128][40];
    int tid = threadIdx.x;
    int wave = tid >> 6, lane = tid & 63;
    int wm = (wave >> 1) * 64, wn = (wave & 1) * 64;
    int m0 = blockIdx.x * 128, n0 = blockIdx.y * 128;

    int r0 = tid >> 2;
    int c8 = (tid & 3) * 8;

    floatx4 acc[4][4];
#pragma unroll
    for (int i = 0; i < 4; i++)
#pragma unroll
        for (int j = 0; j < 4; j++) acc[i][j] = 0;

    int ml = lane & 15, kq = (lane >> 4) * 8;

    for (int k0 = 0; k0 < 384; k0 += 32) {
        short8 a0 = *(const short8*)(Ab + (size_t)(m0 + r0) * 384 + k0 + c8);
        short8 a1 = *(const short8*)(Ab + (size_t)(m0 + r0 + 64) * 384 + k0 + c8);
        short8 b0 = *(const short8*)(Bb + (size_t)(n0 + r0) * 384 + k0 + c8);
        short8 b1 = *(const short8*)(Bb + (size_t)(n0 + r0 + 64) * 384 + k0 + c8);

        __syncthreads();
        *(short8*)(&sA[r0][c8])      = a0;
        *(short8*)(&sA[r0 + 64][c8]) = a1;
        *(short8*)(&sB[r0][c8])      = b0;
        *(short8*)(&sB[r0 + 64][c8]) = b1;
        __syncthreads();

        short8 af[4], bf[4];
#pragma unroll
        for (int i = 0; i < 4; i++)
            af[i] = *(const short8*)(&sA[wm + i * 16 + ml][kq]);
#pragma unroll
        for (int j = 0; j < 4; j++)
            bf[j] = *(const short8*)(&sB[wn + j * 16 + ml][kq]);
#pragma unroll
        for (int i = 0; i < 4; i++)
#pragma unroll
            for (int j = 0; j < 4; j++)
                acc[i][j] = __builtin_amdgcn_mfma_f32_16x16x32_bf16(af[i], bf[j], acc[i][j], 0, 0, 0);
    }

    int cn = lane & 15, rq = (lane >> 4) * 4;
#pragma unroll
    for (int i = 0; i < 4; i++)
#pragma unroll
        for (int j = 0; j < 4; j++)
#pragma unroll
            for (int r = 0; r < 4; r++)
                Cb[(size_t)(m0 + wm + i * 16 + rq + r) * NHC + n0 + wn + j * 16 + cn] = f2b(acc[i][j][r]);
}

__global__ __launch_bounds__(256) void att_score_kernel(
    const unsigned short* __restrict__ h_bf,
    const float* __restrict__ att_src,
    const float* __restrict__ att_dst,
    float* __restrict__ a_src, float* __restrict__ a_dst)
{
    int w = (blockIdx.x * 256 + threadIdx.x) >> 6;
    int lane = threadIdx.x & 63;
    int n = w / 3, hd = w % 3;
    const unsigned short* hrow = h_bf + (size_t)n * NHC + hd * CDIM;
    float s0 = 0.f, s1 = 0.f;
#pragma unroll
    for (int q = 0; q < 6; q++) {
        int c = lane + q * 64;
        float hv = b2f(hrow[c]);
        s0 += hv * att_src[hd * CDIM + c];
        s1 += hv * att_dst[hd * CDIM + c];
    }
#pragma unroll
    for (int off = 32; off; off >>= 1) {
        s0 += __shfl_down(s0, off, 64);
        s1 += __shfl_down(s1, off, 64);
    }
    if (lane == 0) { a_src[n * 3 + hd] = s0; a_dst[n * 3 + hd] = s1; }
}

__global__ void edge_const_kernel(const float* __restrict__ Wedge,
                                  const float* __restrict__ att_edge,
                                  float* __restrict__ Kh)
{
    int hd = threadIdx.x >> 6, lane = threadIdx.x & 63;
    float s = 0.f;
#pragma unroll
    for (int q = 0; q < 6; q++) {
        int c = lane + q * 64;
        s += Wedge[hd * CDIM + c] * att_edge[hd * CDIM + c];
    }
#pragma unroll
    for (int off = 32; off; off >>= 1) s += __shfl_down(s, off, 64);
    if (lane == 0) Kh[hd] = s;
}

__global__ __launch_bounds__(256) void edge_score_kernel(
    const int* __restrict__ edge_index,
    const float* __restrict__ edge_attr,
    const float* __restrict__ a_src, const float* __restrict__ a_dst,
    const float* __restrict__ Kh,
    float* __restrict__ a_raw, unsigned* __restrict__ amax_enc,
    int* __restrict__ deg)
{
    int tid = blockIdx.x * 256 + threadIdx.x;
    int hd = tid >> 16;
    int e = tid & (E_EDGES - 1);
    int src = edge_index[e];
    int dst = edge_index[E_EDGES + e];
    float a = a_src[src * 3 + hd] + a_dst[dst * 3 + hd] + edge_attr[e] * Kh[hd];
    a = a > 0.f ? a : 0.2f * a;
    a_raw[hd * E_EDGES + e] = a;
    atomicMax(&amax_enc[dst * 3 + hd], enc_f(a));
    if (hd == 0) atomicAdd(&deg[dst], 1);
}

__global__ __launch_bounds__(256) void scan_kernel(
    const int* __restrict__ deg, int* __restrict__ rowstart, int* __restrict__ cursor)
{
    __shared__ int ps[256];
    int t = threadIdx.x;
    int l[32], s = 0;
#pragma unroll
    for (int i = 0; i < 32; i++) { l[i] = deg[t * 32 + i]; s += l[i]; }
    ps[t] = s;
    __syncthreads();
    if (t == 0) {
        int run = 0;
        for (int i = 0; i < 256; i++) { int v = ps[i]; ps[i] = run; run += v; }
    }
    __syncthreads();
    int b = ps[t];
#pragma unroll
    for (int i = 0; i < 32; i++) {
        rowstart[t * 32 + i] = b;
        cursor[t * 32 + i] = b;
        b += l[i];
    }
}

__global__ __launch_bounds__(256) void edge_exp_kernel(
    const int* __restrict__ edge_index,
    const float* __restrict__ a_raw, const unsigned* __restrict__ amax_enc,
    float* __restrict__ w_exp, float* __restrict__ denom,
    int* __restrict__ cursor, int* __restrict__ csr_e)
{
    int tid = blockIdx.x * 256 + threadIdx.x;
    int hd = tid >> 16;
    int e = tid & (E_EDGES - 1);
    int dst = edge_index[E_EDGES + e];
    float m = dec_f(amax_enc[dst * 3 + hd]);
    float w = expf(a_raw[hd * E_EDGES + e] - m);
    w_exp[hd * E_EDGES + e] = w;
    unsafeAtomicAdd(&denom[dst * 3 + hd], w);
    if (hd == 0) {
        int pos = atomicAdd(&cursor[dst], 1);
        csr_e[pos] = e;
    }
}

// CSR aggregation fused with head-mean+bias, predictor MLP, out_pred write.
__global__ __launch_bounds__(384) void aggregate_fused(
    const int* __restrict__ flag,
    const int* __restrict__ edge_index,
    const unsigned short* __restrict__ h_bf,
    const float* __restrict__ w_exp, const float* __restrict__ denom,
    const int* __restrict__ rowstart, const int* __restrict__ deg,
    const int* __restrict__ csr_e,
    const float* __restrict__ gat_bias,
    const float* __restrict__ Wp1, const float* __restrict__ bp1,
    const float* __restrict__ Wp3, const float* __restrict__ bp3,
    float* __restrict__ gmean,
    void* __restrict__ out_pred)
{
    int dst = blockIdx.x;
    int s = rowstart[dst], d = deg[dst];
    int tid = threadIdx.x;
    const float third = 1.f / 3.f;
    float inv0 = third / (denom[dst * 3 + 0] + 1e-16f);
    float inv1 = third / (denom[dst * 3 + 1] + 1e-16f);
    float inv2 = third / (denom[dst * 3 + 2] + 1e-16f);
    __shared__ int ssrc[64];
    __shared__ float sc0[64], sc1[64], sc2[64];
    __shared__ float gs[384];
    __shared__ float ps[12];
    float a = 0.f;
    for (int ch = 0; ch < d; ch += 64) {
        int m = d - ch; if (m > 64) m = 64;
        __syncthreads();
        if (tid < m) {
            int e = csr_e[s + ch + tid];
            ssrc[tid] = edge_index[e];
            sc0[tid] = w_exp[e] * inv0;
            sc1[tid] = w_exp[E_EDGES + e] * inv1;
            sc2[tid] = w_exp[2 * E_EDGES + e] * inv2;
        }
        __syncthreads();
        for (int i = 0; i < m; i++) {
            const unsigned short* hs = h_bf + (size_t)ssrc[i] * NHC;
            a += sc0[i] * b2f(hs[tid]) + sc1[i] * b2f(hs[tid + CDIM]) + sc2[i] * b2f(hs[tid + 2 * CDIM]);
        }
    }
    float g = a + gat_bias[tid];
    gmean[(size_t)dst * CDIM + tid] = g;
    gs[tid] = g;
    __syncthreads();

    int t = tid >> 5, c = tid & 31;
    float v = gs[t * 32 + c] * Wp1[c];
#pragma unroll
    for (int off = 16; off; off >>= 1) v += __shfl_down(v, off, 32);
    if (c == 0) { float p = v + bp1[0]; ps[t] = p > 0.f ? p : 0.f; }
    __syncthreads();

    if (tid < PRED_LEN) {
        float acc = bp3[tid];
#pragma unroll
        for (int tt = 0; tt < 12; tt++) acc += Wp3[tid * 12 + tt] * ps[tt];
        acc = acc > 0.f ? acc : 0.f;
        size_t oi = (size_t)dst * PRED_LEN + tid;
        if (*flag) ((__hip_bfloat16*)out_pred)[oi] = __float2bfloat16(acc);
        else       ((float*)out_pred)[oi] = acc;
    }
}

// two-stage batch max-pool: grid (8 batches, 16 chunks), 384 threads
__global__ __launch_bounds__(384) void pool_kernel(
    const float* __restrict__ gmean,
    unsigned* __restrict__ pooled_enc)
{
    int b = blockIdx.x, ch = blockIdx.y;
    int tid = threadIdx.x;
    const float* base = gmean + ((size_t)b * 1024 + ch * 64) * CDIM + tid;
    float m = -3.4e38f;
    for (int i = 0; i < 64; i++)
        m = fmaxf(m, base[(size_t)i * CDIM]);
    atomicMax(&pooled_enc[b * CDIM + tid], enc_f(m));
}

__global__ __launch_bounds__(256) void cls_kernel(
    const int* __restrict__ flag,
    const unsigned* __restrict__ pooled_enc,
    const float* __restrict__ Wc1, const float* __restrict__ bc1,
    const float* __restrict__ Wc2, const float* __restrict__ bc2,
    void* __restrict__ out_base)
{
    __shared__ float l1s[8][32];
    int b = threadIdx.x >> 5, i = threadIdx.x & 31;
    float acc = bc1[i];
    for (int c = 0; c < CDIM; c++)
        acc += Wc1[i * CDIM + c] * dec_f(pooled_enc[b * CDIM + c]);
    l1s[b][i] = acc;
    __syncthreads();
    if (threadIdx.x < 8) {
        int bb = threadIdx.x;
        float l0 = bc2[0], l1v = bc2[1];
#pragma unroll
        for (int ii = 0; ii < 32; ii++) {
            l0  += Wc2[ii] * l1s[bb][ii];
            l1v += Wc2[32 + ii] * l1s[bb][ii];
        }
        float m = fmaxf(l0, l1v);
        float e0 = expf(l0 - m), e1 = expf(l1v - m);
        float s = e0 + e1;
        if (*flag) {
            __hip_bfloat16* ob = (__hip_bfloat16*)out_base;
            ob[OUT_LABEL_OFF + bb * 2 + 0] = __float2bfloat16(e0 / s);
            ob[OUT_LABEL_OFF + bb * 2 + 1] = __float2bfloat16(e1 / s);
        } else {
            float* of = (float*)out_base;
            of[OUT_LABEL_OFF + bb * 2 + 0] = e0 / s;
            of[OUT_LABEL_OFF + bb * 2 + 1] = e1 / s;
        }
    }
}

extern "C" void kernel_launch(void* const* d_in, const int* in_sizes, int n_in,
                              void* d_out, int out_size, void* d_ws, size_t ws_size,
                              hipStream_t stream) {
    float* W = (float*)d_ws;
    int* flag = (int*)(W + O_FLAG);
    const int* edge_index = (const int*)d_in[1];

    size_t zero_floats = (size_t)(O_POOLED + 8 * CDIM) - O_AMAX;
    hipMemsetAsync(W + O_AMAX, 0, zero_floats * 4, stream);
    hipMemsetAsync(W + O_DEG, 0, 8192 * 4, stream);

    detect_kernel<<<1, 64, 0, stream>>>((const unsigned short*)d_in[5], flag);
    convert_all<<<(CONV_TOTAL + 255) / 256, 256, 0, stream>>>(
        flag,
        d_in[0], d_in[5], d_in[6], d_in[7], d_in[8],
        d_in[9], d_in[10], d_in[11], d_in[12], d_in[13],
        d_in[14], d_in[15], d_in[16], d_in[17], d_in[18],
        d_in[19], d_in[20], d_in[21], d_in[22], d_in[2],
        W);
    cvt_wgat<<<(442368 + 255) / 256, 256, 0, stream>>>(
        flag, d_in[9], (unsigned short*)(W + O_WGATB));

    gru_kernel<<<N_NODES * 32 / 256, 256, 0, stream>>>(
        W + O_X, W + O_WIH, W + O_WHH, W + O_BIH, W + O_BHH,
        (unsigned short*)(W + O_GATB));
    gemm_mfma<<<dim3(N_NODES / 128, NHC / 128), 256, 0, stream>>>(
        (const unsigned short*)(W + O_GATB),
        (const unsigned short*)(W + O_WGATB),
        (unsigned short*)(W + O_HFEAT));
    att_score_kernel<<<(N_NODES * 3 * 64) / 256, 256, 0, stream>>>(
        (const unsigned short*)(W + O_HFEAT), W + O_ATTS, W + O_ATTD,
        W + O_ASRC, W + O_ADST);
    edge_const_kernel<<<1, 192, 0, stream>>>(W + O_WEDGE, W + O_ATTE, W + O_KH);
    edge_score_kernel<<<3 * E_EDGES / 256, 256, 0, stream>>>(
        edge_index, W + O_EATTR, W + O_ASRC, W + O_ADST, W + O_KH,
        W + O_ARAW, (unsigned*)(W + O_AMAX), (int*)(W + O_DEG));
    scan_kernel<<<1, 256, 0, stream>>>(
        (const int*)(W + O_DEG), (int*)(W + O_ROWST), (int*)(W + O_CURS));
    edge_exp_kernel<<<3 * E_EDGES / 256, 256, 0, stream>>>(
        edge_index, W + O_ARAW, (const unsigned*)(W + O_AMAX),
        W + O_WEXP, W + O_DENOM, (int*)(W + O_CURS), (int*)(W + O_CSRE));
    aggregate_fused<<<N_NODES, 384, 0, stream>>>(
        flag, edge_index, (const unsigned short*)(W + O_HFEAT),
        W + O_WEXP, W + O_DENOM,
        (const int*)(W + O_ROWST), (const int*)(W + O_DEG),
        (const int*)(W + O_CSRE),
        W + O_GBIAS, W + O_WP1, W + O_BP1, W + O_WP3, W + O_BP3,
        W + O_GMEAN, d_out);
    pool_kernel<<<dim3(8, 16), 384, 0, stream>>>(
        W + O_GMEAN, (unsigned*)(W + O_POOLED));
    cls_kernel<<<1, 256, 0, stream>>>(
        flag, (const unsigned*)(W + O_POOLED),
        W + O_WC1, W + O_BC1, W + O_WC2, W + O_BC2, d_out);
}